// Round 2
// baseline (307.531 us; speedup 1.0000x reference)
//
#include <hip/hip_runtime.h>
#include <hip/hip_bf16.h>
#include <cmath>

typedef unsigned short u16;
typedef __attribute__((ext_vector_type(8))) short bf16x8;
typedef __attribute__((ext_vector_type(4))) float f32x4;
typedef __attribute__((ext_vector_type(4))) unsigned short u16x4;

// Problem constants: B=8, C=128, H=128, WIN=4, K=3, WS=64, L=16384
// Workspace layout (bytes):
#define OFF_AGG   0u          // 5 stats * 8b * 4w * 128c f32 = 81920
#define OFF_WW    81920u      // 32 f32
#define OFF_R     82048u      // R2[w][t][c] f32 = 18432
#define OFF_FSUM  100480u     // 128 f32
#define OFF_GKT   100992u     // 4*128*128 f32 = 262144
#define OFF_A     363136u     // A2[w][t][o][c] f32 = 2359296
#define OFF_P     2722432u    // P2[w][t][o][j] f32 = 2359296
#define OFF_M     5081728u    // M[w][t][o][c] f32 = 2359296
#define OFF_KEFF  7441024u    // keff[b][t][o][c] u16 = 2359296 ; cw2 (f32, same size) lives here during prep
#define OFF_XPAD  9800320u    // [b][130][130][128] u16 = 34611200  (total ~44.4 MB)

__device__ __forceinline__ u16 f2bf(float f) {
  union { float f; unsigned int u; } v; v.f = f;
  unsigned int r = v.u + 0x7FFFu + ((v.u >> 16) & 1u);
  return (u16)(r >> 16);
}

// K1: fp32 x -> padded bf16 image [b][130][130][128]; window boundary aggregates via atomics.
// agg stats: 0=T 1=rowFirst 2=rowLast 3=colFirst 4=colLast, layout [stat][b][w][c]
__global__ void k1_pad_agg(const float* __restrict__ x, u16* __restrict__ xpad,
                           float* __restrict__ agg) {
  const int c = threadIdx.x;      // 0..127
  const int rp = blockIdx.x;      // padded row 0..129
  const int b = blockIdx.y;
  const size_t xpb = ((size_t)b * 130 + rp) * 130 * 128;
  if (rp == 0 || rp == 129) {
    for (int q = 0; q < 130; ++q) xpad[xpb + (size_t)q * 128 + c] = 0;
    return;
  }
  const int r = rp - 1;
  xpad[xpb + c] = 0;
  xpad[xpb + (size_t)129 * 128 + c] = 0;
  const float* xr = x + ((size_t)b * 16384 + (size_t)r * 128) * 128 + c;
  float t0 = 0.f, t1 = 0.f, cF0 = 0.f, cL0 = 0.f, cF1 = 0.f, cL1 = 0.f;
  #pragma unroll 4
  for (int q = 0; q < 128; ++q) {
    float v = xr[(size_t)q * 128];
    xpad[xpb + (size_t)(q + 1) * 128 + c] = f2bf(v);
    if (q < 64) t0 += v; else t1 += v;
    if (q == 0) cF0 = v;
    if (q == 63) cL0 = v;
    if (q == 64) cF1 = v;
    if (q == 127) cL1 = v;
  }
  const int i = r >> 6, rw = r & 63;
  const int a0 = b * 512 + (i * 2) * 128 + c;
  const int a1 = b * 512 + (i * 2 + 1) * 128 + c;
  atomicAdd(&agg[a0], t0);
  atomicAdd(&agg[a1], t1);
  atomicAdd(&agg[3 * 4096 + a0], cF0);
  atomicAdd(&agg[3 * 4096 + a1], cF1);
  atomicAdd(&agg[4 * 4096 + a0], cL0);
  atomicAdd(&agg[4 * 4096 + a1], cL1);
  if (rw == 0)  { atomicAdd(&agg[4096 + a0], t0); atomicAdd(&agg[4096 + a1], t1); }
  if (rw == 63) { atomicAdd(&agg[2 * 4096 + a0], t0); atomicAdd(&agg[2 * 4096 + a1], t1); }
}

// kCW: cw2[w][t][oc][cin] = conv1_w[(w*128+oc)][cin][t]  (one-time 2.36MB transpose)
__global__ void kCW(const float* __restrict__ conv1_w, float* __restrict__ cw2) {
  int gid = blockIdx.x * 256 + threadIdx.x;   // 0..589823
  int wtl = gid >> 14;                        // w*9+t, 0..35
  int w = wtl / 9, t = wtl % 9;
  int oc = (gid >> 7) & 127, cin = gid & 127;
  cw2[gid] = conv1_w[((size_t)(w * 128 + oc) * 128 + cin) * 9 + t];
}

// k_small (fused): R2[w][t][c] = sum_oc dc_w[w,oc]*cw2[w,t,oc,c]
//                  gkT[w][j][c] = gk_w[c][w][j]
//                  fsum[o] = sum_oc fusion_w[o, 512+oc]
__global__ void k_small(const float* __restrict__ dc_w, const float* __restrict__ cw2,
                        const float* __restrict__ gk_w, const float* __restrict__ fusion_w,
                        float* __restrict__ R2, float* __restrict__ gkT,
                        float* __restrict__ fsum) {
  const int bid = blockIdx.x;
  const int tid = threadIdx.x;
  if (bid < 18) {
    int pi = bid * 2 + (tid >> 7);            // (w*9+t) 0..35
    int w = pi / 9;
    int c = tid & 127;
    const float* cwp = cw2 + (size_t)pi * 16384 + c;
    const float* dw = dc_w + w * 128;
    float s = 0.f;
    for (int oc = 0; oc < 128; ++oc) s += dw[oc] * cwp[(size_t)oc * 128];
    R2[pi * 128 + c] = s;
  } else if (bid < 274) {
    int gid = (bid - 18) * 256 + tid;         // 0..65535
    int w = gid >> 14, j = (gid >> 7) & 127, c = gid & 127;
    gkT[gid] = gk_w[c * 512 + w * 128 + j];
  } else if (tid < 128) {
    float s = 0.f;
    for (int oc = 0; oc < 128; ++oc) s += fusion_w[tid * 640 + 512 + oc];
    fsum[tid] = s;
  }
}

// K2: per-batch SE gate ww[b][w] from aggregates (S trick) + exact-gelu MLP + sigmoid
__global__ void k2_ww(const float* __restrict__ x, const float* __restrict__ agg,
                      const float* __restrict__ R2, const float* __restrict__ dc_b,
                      const float* __restrict__ l1_w, const float* __restrict__ l1_b,
                      const float* __restrict__ l2_w, const float* __restrict__ l2_b,
                      float* __restrict__ ww) {
  const int b = blockIdx.x;
  const int tid = threadIdx.x;
  const int w = tid >> 6, lane = tid & 63;
  __shared__ float red[4];
  float partial = 0.f;
  const int i = w >> 1, j = w & 1;
  const int r0 = i * 64, s0 = j * 64;
  const size_t base = (size_t)b * 16384 * 128;
  #pragma unroll
  for (int k = 0; k < 2; ++k) {
    const int c = lane * 2 + k;
    const int ai = b * 512 + w * 128 + c;
    float T  = agg[ai];
    float rF = agg[4096 + ai];
    float rL = agg[2 * 4096 + ai];
    float cF = agg[3 * 4096 + ai];
    float cL = agg[4 * 4096 + ai];
    float c00 = x[base + ((size_t)(r0 + 0)  * 128 + (s0 + 0))  * 128 + c];
    float c0L = x[base + ((size_t)(r0 + 0)  * 128 + (s0 + 63)) * 128 + c];
    float cL0 = x[base + ((size_t)(r0 + 63) * 128 + (s0 + 0))  * 128 + c];
    float cLL = x[base + ((size_t)(r0 + 63) * 128 + (s0 + 63)) * 128 + c];
    float S[9];
    S[0] = T - rL - cL + cLL;
    S[1] = T - rL;
    S[2] = T - rL - cF + cL0;
    S[3] = T - cL;
    S[4] = T;
    S[5] = T - cF;
    S[6] = T - rF - cL + c0L;
    S[7] = T - rF;
    S[8] = T - rF - cF + c00;
    #pragma unroll
    for (int t = 0; t < 9; ++t) partial += S[t] * R2[((w * 9 + t) << 7) + c];
  }
  for (int off = 32; off > 0; off >>= 1) partial += __shfl_xor(partial, off, 64);
  if (lane == 0) red[w] = partial;
  __syncthreads();
  if (tid == 0) {
    float ww0[4];
    #pragma unroll
    for (int w2 = 0; w2 < 4; ++w2) ww0[w2] = red[w2] * (1.f / 4096.f) + dc_b[w2];
    float h1[16];
    for (int i2 = 0; i2 < 16; ++i2) {
      float s = l1_b[i2];
      #pragma unroll
      for (int w2 = 0; w2 < 4; ++w2) s += l1_w[i2 * 4 + w2] * ww0[w2];
      h1[i2] = 0.5f * s * (1.f + erff(s * 0.70710678118654752f));
    }
    for (int w2 = 0; w2 < 4; ++w2) {
      float s = l2_b[w2];
      for (int i2 = 0; i2 < 16; ++i2) s += l2_w[w2 * 16 + i2] * h1[i2];
      ww[b * 4 + w2] = 1.f / (1.f + expf(-s));
    }
  }
}

// K3: A2[w,t,o,c] = sum_i fusion_w[o, w*128+i]*cw2[w,t,i,c]
//     P2[w,t,o,j] = sum_i fusion_w[o, 512+i]  *cw2[w,t,i,j]
// block = (w*9+t)*8 + og; thread = (o within og-group of 16) x (c-octet)
__global__ void k3_AP(const float* __restrict__ fusion_w, const float* __restrict__ cw2,
                      float* __restrict__ A2, float* __restrict__ P2) {
  const int wt = blockIdx.x >> 3;             // 0..35
  const int og = blockIdx.x & 7;
  const int w = wt / 9;
  const int o = og * 16 + (threadIdx.x >> 4);
  const int c = (threadIdx.x & 15) * 8;
  const float* f1 = fusion_w + o * 640 + w * 128;
  const float* f4 = fusion_w + o * 640 + 512;
  const float* cwp = cw2 + (size_t)wt * 16384 + c;
  float a[8] = {0,0,0,0,0,0,0,0}, p[8] = {0,0,0,0,0,0,0,0};
  for (int i = 0; i < 128; ++i) {
    float v1 = f1[i], v4 = f4[i];
    float4 c0 = *(const float4*)(cwp + (size_t)i * 128);
    float4 c1 = *(const float4*)(cwp + (size_t)i * 128 + 4);
    a[0] += v1 * c0.x; a[1] += v1 * c0.y; a[2] += v1 * c0.z; a[3] += v1 * c0.w;
    a[4] += v1 * c1.x; a[5] += v1 * c1.y; a[6] += v1 * c1.z; a[7] += v1 * c1.w;
    p[0] += v4 * c0.x; p[1] += v4 * c0.y; p[2] += v4 * c0.z; p[3] += v4 * c0.w;
    p[4] += v4 * c1.x; p[5] += v4 * c1.y; p[6] += v4 * c1.z; p[7] += v4 * c1.w;
  }
  const size_t oidx = ((size_t)wt * 128 + o) * 128 + c;
  *(float4*)(A2 + oidx)     = make_float4(a[0], a[1], a[2], a[3]);
  *(float4*)(A2 + oidx + 4) = make_float4(a[4], a[5], a[6], a[7]);
  *(float4*)(P2 + oidx)     = make_float4(p[0], p[1], p[2], p[3]);
  *(float4*)(P2 + oidx + 4) = make_float4(p[4], p[5], p[6], p[7]);
}

// K4: M[w][t][o][c] = A2[w,t,o,c] + sum_j P2[w,t,o,j] * gkT[w][j][c]
__global__ void k4_M(const float* __restrict__ A2, const float* __restrict__ P2,
                     const float* __restrict__ gkT, float* __restrict__ M) {
  const int wt = blockIdx.x >> 3;
  const int og = blockIdx.x & 7;
  const int w = wt / 9;
  const int o = og * 16 + (threadIdx.x >> 4);
  const int c = (threadIdx.x & 15) * 8;
  const size_t oidx = ((size_t)wt * 128 + o) * 128 + c;
  float4 a0 = *(const float4*)(A2 + oidx);
  float4 a1 = *(const float4*)(A2 + oidx + 4);
  float acc[8] = {a0.x, a0.y, a0.z, a0.w, a1.x, a1.y, a1.z, a1.w};
  const float* Pp = P2 + ((size_t)wt * 128 + o) * 128;
  const float* g = gkT + w * 16384 + c;
  for (int j = 0; j < 128; ++j) {
    float pv = Pp[j];
    float4 g0 = *(const float4*)(g + (size_t)j * 128);
    float4 g1 = *(const float4*)(g + (size_t)j * 128 + 4);
    acc[0] += pv * g0.x; acc[1] += pv * g0.y; acc[2] += pv * g0.z; acc[3] += pv * g0.w;
    acc[4] += pv * g1.x; acc[5] += pv * g1.y; acc[6] += pv * g1.z; acc[7] += pv * g1.w;
  }
  float* Mo = M + (size_t)wt * 16384 + o * 128 + c;
  *(float4*)(Mo)     = make_float4(acc[0], acc[1], acc[2], acc[3]);
  *(float4*)(Mo + 4) = make_float4(acc[4], acc[5], acc[6], acc[7]);
}

// K5: Keff_bf16[b][t][o][c] = sum_w ww[b,w]*M[w][t][o][c] + fsum[o]*gk_b[c]
__global__ void k5_keff(const float* __restrict__ M, const float* __restrict__ ww,
                        const float* __restrict__ fsum, const float* __restrict__ gk_b,
                        u16* __restrict__ keff) {
  int gid = blockIdx.x * 256 + threadIdx.x;   // 0..294911
  int b = gid / 36864;
  int rem = gid % 36864;                      // t*4096 + o*32 + cq
  int o = (rem % 4096) / 32;
  int c = (rem % 32) * 4;
  float w0 = ww[b * 4 + 0], w1 = ww[b * 4 + 1], w2 = ww[b * 4 + 2], w3 = ww[b * 4 + 3];
  int mi = rem * 4;                           // == t*16384 + o*128 + c
  float4 m0 = *(const float4*)(M + 0 * 147456 + mi);
  float4 m1 = *(const float4*)(M + 1 * 147456 + mi);
  float4 m2 = *(const float4*)(M + 2 * 147456 + mi);
  float4 m3 = *(const float4*)(M + 3 * 147456 + mi);
  float fs = fsum[o];
  float4 gb = *(const float4*)(gk_b + c);
  float r0 = w0 * m0.x + w1 * m1.x + w2 * m2.x + w3 * m3.x + fs * gb.x;
  float r1 = w0 * m0.y + w1 * m1.y + w2 * m2.y + w3 * m3.y + fs * gb.y;
  float r2 = w0 * m0.z + w1 * m1.z + w2 * m2.z + w3 * m3.z + fs * gb.z;
  float r3 = w0 * m0.w + w1 * m1.w + w2 * m2.w + w3 * m3.w + fs * gb.w;
  u16x4 st = { f2bf(r0), f2bf(r1), f2bf(r2), f2bf(r3) };
  *(u16x4*)(keff + (size_t)b * 147456 + mi) = st;
}

// K6: per-batch 3x3 C->C conv as 9 accumulated bf16 MFMA GEMMs.
// Block = one (b, image row p): out tile 128 px x 128 o; 4 waves in 2x2 (64m x 64n each).
// Single 32KB LDS weight buffer (XOR-swizzled, conflict-free) + register prefetch of next tap.
// 32KB LDS + 88 VGPR -> 4 blocks/CU resident (grid 1024 = exactly 4/CU).
__global__ __launch_bounds__(256, 4) void k6_conv(
    const u16* __restrict__ xpad, const u16* __restrict__ keff,
    const float* __restrict__ fusion_b, float* __restrict__ out) {
  __shared__ __align__(16) u16 wlds[128 * 128];
  const int tid = threadIdx.x;
  const int blk = blockIdx.x;
  const int b = blk & 7;            // XCD affinity: batch <-> XCD
  const int p = blk >> 3;
  const int wid = tid >> 6;
  const int lane = tid & 63;
  const int wm = (wid & 1) * 64;
  const int wn = (wid >> 1) * 64;
  const int quad = lane >> 4;
  const int l16 = lane & 15;

  f32x4 acc[4][4];
  #pragma unroll
  for (int i = 0; i < 4; ++i)
    #pragma unroll
    for (int j = 0; j < 4; ++j)
      acc[i][j] = (f32x4){0.f, 0.f, 0.f, 0.f};

  const u16* kb = keff + (size_t)b * 147456;
  bf16x8 streg[8];

  auto stage_load = [&](int tap) {
    const u16* src = kb + tap * 16384;
    #pragma unroll
    for (int it = 0; it < 8; ++it)
      streg[it] = *(const bf16x8*)(src + (it * 256 + tid) * 8);
  };
  // XOR swizzle: element row n (o-channel), col-octet cb -> offset n*128 + ((cb^(n&15))*8)
  auto stage_write = [&]() {
    #pragma unroll
    for (int it = 0; it < 8; ++it) {
      int e = it * 256 + tid;
      int n = e >> 4, cb = e & 15;
      *(bf16x8*)(&wlds[(n << 7) + ((cb ^ (n & 15)) << 3)]) = streg[it];
    }
  };

  stage_load(0);
  stage_write();
  __syncthreads();

  const size_t xrow = 130 * 128;
  const u16* xb = xpad + (size_t)b * 130 * xrow;

  for (int tap = 0; tap < 9; ++tap) {
    if (tap < 8) stage_load(tap + 1);           // global->reg, overlaps MFMA below
    const int dh = tap / 3 - 1;
    const int dw = tap % 3 - 1;
    const u16* arow = xb + (size_t)(p + 1 + dh) * xrow + (size_t)(1 + dw) * 128;
    #pragma unroll
    for (int kc = 0; kc < 4; ++kc) {
      const int c0 = kc * 32 + quad * 8;
      const int cb = kc * 4 + quad;             // col-octet index
      bf16x8 a[4], bb[4];
      #pragma unroll
      for (int i = 0; i < 4; ++i)
        a[i] = *(const bf16x8*)(arow + (size_t)(wm + i * 16 + l16) * 128 + c0);
      #pragma unroll
      for (int j = 0; j < 4; ++j) {
        int n = wn + j * 16 + l16;              // n&15 == l16
        bb[j] = *(const bf16x8*)(&wlds[(n << 7) + ((cb ^ l16) << 3)]);
      }
      #pragma unroll
      for (int i = 0; i < 4; ++i)
        #pragma unroll
        for (int j = 0; j < 4; ++j)
          acc[i][j] = __builtin_amdgcn_mfma_f32_16x16x32_bf16(a[i], bb[j], acc[i][j], 0, 0, 0);
    }
    __syncthreads();                            // all waves done reading wlds
    if (tap < 8) {
      stage_write();
      __syncthreads();                          // writes visible to all waves
    }
  }

  float fb[4];
  #pragma unroll
  for (int j = 0; j < 4; ++j) fb[j] = fusion_b[wn + j * 16 + l16];
  float* outb = out + ((size_t)b * 16384 + (size_t)p * 128) * 128;
  #pragma unroll
  for (int i = 0; i < 4; ++i)
    #pragma unroll
    for (int r = 0; r < 4; ++r) {
      const int m = wm + i * 16 + quad * 4 + r;
      #pragma unroll
      for (int j = 0; j < 4; ++j)
        outb[(size_t)m * 128 + (wn + j * 16 + l16)] = acc[i][j][r] + fb[j];
    }
}

extern "C" void kernel_launch(void* const* d_in, const int* in_sizes, int n_in,
                              void* d_out, int out_size, void* d_ws, size_t ws_size,
                              hipStream_t stream) {
  const float* x        = (const float*)d_in[0];
  const float* conv1_w  = (const float*)d_in[1];
  const float* dc_w     = (const float*)d_in[2];
  const float* dc_b     = (const float*)d_in[3];
  const float* l1_w     = (const float*)d_in[4];
  const float* l1_b     = (const float*)d_in[5];
  const float* l2_w     = (const float*)d_in[6];
  const float* l2_b     = (const float*)d_in[7];
  const float* gk_w     = (const float*)d_in[8];
  const float* gk_b     = (const float*)d_in[9];
  const float* fusion_w = (const float*)d_in[10];
  const float* fusion_b = (const float*)d_in[11];
  float* out = (float*)d_out;
  char* ws = (char*)d_ws;

  float* agg  = (float*)(ws + OFF_AGG);
  float* ww   = (float*)(ws + OFF_WW);
  float* R2   = (float*)(ws + OFF_R);
  float* fsum = (float*)(ws + OFF_FSUM);
  float* gkT  = (float*)(ws + OFF_GKT);
  float* A2   = (float*)(ws + OFF_A);
  float* P2   = (float*)(ws + OFF_P);
  float* M    = (float*)(ws + OFF_M);
  float* cw2  = (float*)(ws + OFF_KEFF);   // cw2 (prep) and keff share the slot:
  u16* keff   = (u16*)(ws + OFF_KEFF);     // cw2 is dead before k5 writes keff
  u16* xpad   = (u16*)(ws + OFF_XPAD);

  hipMemsetAsync(agg, 0, 81920, stream);
  k1_pad_agg<<<dim3(130, 8), 128, 0, stream>>>(x, xpad, agg);
  kCW<<<2304, 256, 0, stream>>>(conv1_w, cw2);
  k_small<<<275, 256, 0, stream>>>(dc_w, cw2, gk_w, fusion_w, R2, gkT, fsum);
  k2_ww<<<8, 256, 0, stream>>>(x, agg, R2, dc_b, l1_w, l1_b, l2_w, l2_b, ww);
  k3_AP<<<288, 256, 0, stream>>>(fusion_w, cw2, A2, P2);
  k4_M<<<288, 256, 0, stream>>>(A2, P2, gkT, M);
  k5_keff<<<1152, 256, 0, stream>>>(M, ww, fsum, gk_b, keff);
  k6_conv<<<1024, 256, 0, stream>>>(xpad, keff, fusion_b, out);
}

// Round 4
// 299.209 us; speedup vs baseline: 1.0278x; 1.0278x over previous
//
#include <hip/hip_runtime.h>
#include <hip/hip_bf16.h>
#include <cmath>

typedef unsigned short u16;
typedef __attribute__((ext_vector_type(8))) short bf16x8;
typedef __attribute__((ext_vector_type(4))) float f32x4;
typedef __attribute__((ext_vector_type(2))) unsigned short u16x2;
typedef __attribute__((ext_vector_type(4))) unsigned short u16x4;

// Problem constants: B=8, C=128, H=128, WIN=4, K=3, WS=64, L=16384
// Workspace layout (bytes):
#define OFF_AGG   0u          // 5 stats * 8b * 4w * 128c f32 = 81920
#define OFF_WW    81920u      // 32 f32
#define OFF_R     82048u      // R2[w][t][c] f32 = 18432
#define OFF_FSUM  100480u     // 128 f32
#define OFF_GKT   100992u     // 4*128*128 f32 = 262144
#define OFF_M     5081728u    // M[w][t][o][c] f32 = 2359296
#define OFF_KEFF  7441024u    // keff[b][t][o][c] u16 = 2359296 ; cw2 (f32) lives here during prep
#define OFF_XPAD  9800320u    // [b][130][130][128] u16 = 34611200

__device__ __forceinline__ u16 f2bf(float f) {
  union { float f; unsigned int u; } v; v.f = f;
  unsigned int r = v.u + 0x7FFFu + ((v.u >> 16) & 1u);
  return (u16)(r >> 16);
}

// K1: fp32 x -> padded bf16 image [b][130][130][128]; window boundary aggregates via atomics.
// agg stats: 0=T 1=rowFirst 2=rowLast 3=colFirst 4=colLast, layout [stat][b][w][c]
// 512 threads: qq = tid>>6 (column-quarter-of-16), cp = tid&63 (channel pair).
__global__ void k1_pad_agg(const float* __restrict__ x, u16* __restrict__ xpad,
                           float* __restrict__ agg) {
  const int rp = blockIdx.x;      // padded row 0..129
  const int b = blockIdx.y;
  const int tid = threadIdx.x;
  const size_t xpb = ((size_t)b * 130 + rp) * 130 * 128;
  if (rp == 0 || rp == 129) {
    u16x2 z = {0, 0};
    for (int idx = tid; idx < 8320; idx += 512)
      *(u16x2*)(xpad + xpb + (size_t)idx * 2) = z;
    return;
  }
  const int r = rp - 1;
  const int qq = tid >> 6;        // 0..7, q in [qq*16, qq*16+16)
  const int cp = tid & 63;
  const int c = cp * 2;
  // left/right padding columns
  u16x2 z = {0, 0};
  if (qq == 0) *(u16x2*)(xpad + xpb + c) = z;
  if (qq == 1) *(u16x2*)(xpad + xpb + (size_t)129 * 128 + c) = z;
  const float* xr = x + ((size_t)b * 16384 + (size_t)r * 128 + qq * 16) * 128 + c;
  u16* xpw = xpad + xpb + (size_t)(qq * 16 + 1) * 128 + c;
  float t0 = 0.f, t1 = 0.f;       // window-total partials for the 2 channels
  float cf0 = 0.f, cf1 = 0.f, cl0 = 0.f, cl1 = 0.f;
  #pragma unroll
  for (int q = 0; q < 16; ++q) {
    float2 v = *(const float2*)(xr + (size_t)q * 128);
    u16x2 bv = { f2bf(v.x), f2bf(v.y) };
    *(u16x2*)(xpw + (size_t)q * 128) = bv;
    t0 += v.x; t1 += v.y;
    if (q == 0)  { cf0 = v.x; cf1 = v.y; }
    if (q == 15) { cl0 = v.x; cl1 = v.y; }
  }
  const int i = r >> 6, rw = r & 63, jw = qq >> 2;
  const int a0 = b * 512 + (i * 2 + jw) * 128 + c;
  atomicAdd(&agg[a0], t0);
  atomicAdd(&agg[a0 + 1], t1);
  if (rw == 0)  { atomicAdd(&agg[4096 + a0], t0); atomicAdd(&agg[4096 + a0 + 1], t1); }
  if (rw == 63) { atomicAdd(&agg[2 * 4096 + a0], t0); atomicAdd(&agg[2 * 4096 + a0 + 1], t1); }
  if (qq == 0 || qq == 4) { atomicAdd(&agg[3 * 4096 + a0], cf0); atomicAdd(&agg[3 * 4096 + a0 + 1], cf1); }
  if (qq == 3 || qq == 7) { atomicAdd(&agg[4 * 4096 + a0], cl0); atomicAdd(&agg[4 * 4096 + a0 + 1], cl1); }
}

// kCW: cw2[w][t][oc][cin] = conv1_w[(w*128+oc)][cin][t]  (one-time 2.36MB transpose)
__global__ void kCW(const float* __restrict__ conv1_w, float* __restrict__ cw2) {
  int gid = blockIdx.x * 256 + threadIdx.x;   // 0..589823
  int wtl = gid >> 14;                        // w*9+t, 0..35
  int w = wtl / 9, t = wtl % 9;
  int oc = (gid >> 7) & 127, cin = gid & 127;
  cw2[gid] = conv1_w[((size_t)(w * 128 + oc) * 128 + cin) * 9 + t];
}

// k_small (fused): blocks 0..35: R2[pi][c] = sum_oc dc_w[w,oc]*cw2[pi,oc,c]  (K-split + LDS reduce)
//                  blocks 36..291: gkT[w][j][c] = gk_w[c][w][j]
//                  block 292: fsum[o] = sum_oc fusion_w[o, 512+oc]  (float4, 32 iters = all 128)
__global__ void k_small(const float* __restrict__ dc_w, const float* __restrict__ cw2,
                        const float* __restrict__ gk_w, const float* __restrict__ fusion_w,
                        float* __restrict__ R2, float* __restrict__ gkT,
                        float* __restrict__ fsum) {
  const int bid = blockIdx.x;
  const int tid = threadIdx.x;
  if (bid < 36) {
    __shared__ float red[2][128];
    int pi = bid, w = pi / 9;
    int oh = tid >> 7, c = tid & 127;
    const float* cwp = cw2 + (size_t)pi * 16384 + (size_t)oh * 64 * 128 + c;
    const float* dw = dc_w + w * 128 + oh * 64;
    float s = 0.f;
    for (int oc = 0; oc < 64; ++oc) s += dw[oc] * cwp[(size_t)oc * 128];
    red[oh][c] = s;
    __syncthreads();
    if (oh == 0) R2[pi * 128 + c] = red[0][c] + red[1][c];
  } else if (bid < 292) {
    int gid = (bid - 36) * 256 + tid;         // 0..65535
    int w = gid >> 14, j = (gid >> 7) & 127, c = gid & 127;
    gkT[gid] = gk_w[c * 512 + w * 128 + j];
  } else if (tid < 128) {
    float s = 0.f;
    #pragma unroll
    for (int it = 0; it < 32; ++it) {          // FIX (r3 bug): 32*4 = all 128 elems
      float4 v = *(const float4*)(fusion_w + tid * 640 + 512 + it * 4);
      s += v.x + v.y + v.z + v.w;
    }
    fsum[tid] = s;
  }
}

// K2: per-batch SE gate ww[b][w] from aggregates (S trick) + exact-gelu MLP + sigmoid
__global__ void k2_ww(const float* __restrict__ x, const float* __restrict__ agg,
                      const float* __restrict__ R2, const float* __restrict__ dc_b,
                      const float* __restrict__ l1_w, const float* __restrict__ l1_b,
                      const float* __restrict__ l2_w, const float* __restrict__ l2_b,
                      float* __restrict__ ww) {
  const int b = blockIdx.x;
  const int tid = threadIdx.x;
  const int w = tid >> 6, lane = tid & 63;
  __shared__ float red[4];
  float partial = 0.f;
  const int i = w >> 1, j = w & 1;
  const int r0 = i * 64, s0 = j * 64;
  const size_t base = (size_t)b * 16384 * 128;
  #pragma unroll
  for (int k = 0; k < 2; ++k) {
    const int c = lane * 2 + k;
    const int ai = b * 512 + w * 128 + c;
    float T  = agg[ai];
    float rF = agg[4096 + ai];
    float rL = agg[2 * 4096 + ai];
    float cF = agg[3 * 4096 + ai];
    float cL = agg[4 * 4096 + ai];
    float c00 = x[base + ((size_t)(r0 + 0)  * 128 + (s0 + 0))  * 128 + c];
    float c0L = x[base + ((size_t)(r0 + 0)  * 128 + (s0 + 63)) * 128 + c];
    float cL0 = x[base + ((size_t)(r0 + 63) * 128 + (s0 + 0))  * 128 + c];
    float cLL = x[base + ((size_t)(r0 + 63) * 128 + (s0 + 63)) * 128 + c];
    float S[9];
    S[0] = T - rL - cL + cLL;
    S[1] = T - rL;
    S[2] = T - rL - cF + cL0;
    S[3] = T - cL;
    S[4] = T;
    S[5] = T - cF;
    S[6] = T - rF - cL + c0L;
    S[7] = T - rF;
    S[8] = T - rF - cF + c00;
    #pragma unroll
    for (int t = 0; t < 9; ++t) partial += S[t] * R2[((w * 9 + t) << 7) + c];
  }
  for (int off = 32; off > 0; off >>= 1) partial += __shfl_xor(partial, off, 64);
  if (lane == 0) red[w] = partial;
  __syncthreads();
  if (tid == 0) {
    float ww0[4];
    #pragma unroll
    for (int w2 = 0; w2 < 4; ++w2) ww0[w2] = red[w2] * (1.f / 4096.f) + dc_b[w2];
    float h1[16];
    for (int i2 = 0; i2 < 16; ++i2) {
      float s = l1_b[i2];
      #pragma unroll
      for (int w2 = 0; w2 < 4; ++w2) s += l1_w[i2 * 4 + w2] * ww0[w2];
      h1[i2] = 0.5f * s * (1.f + erff(s * 0.70710678118654752f));
    }
    for (int w2 = 0; w2 < 4; ++w2) {
      float s = l2_b[w2];
      for (int i2 = 0; i2 < 16; ++i2) s += l2_w[w2 * 16 + i2] * h1[i2];
      ww[b * 4 + w2] = 1.f / (1.f + expf(-s));
    }
  }
}

// K34 (fused K3+K4): per block (wt, og of 8 o's):
//   phase1: a4/p4 rows of A/P for (wt,o,c); P-row parked in LDS
//   phase2: M[wt][o][c] = a4 + sum_j P[o][j]*gkT[w][j][c]
__global__ void k34_M(const float* __restrict__ fusion_w, const float* __restrict__ cw2,
                      const float* __restrict__ gkT, float* __restrict__ M) {
  __shared__ float P_lds[8][128];
  const int wt = blockIdx.x >> 4;             // 0..35
  const int og = blockIdx.x & 15;
  const int w = wt / 9;
  const int o_l = threadIdx.x >> 5;           // 0..7
  const int o = og * 8 + o_l;
  const int c = (threadIdx.x & 31) * 4;
  const float* f1 = fusion_w + o * 640 + w * 128;
  const float* f4 = fusion_w + o * 640 + 512;
  const float* cwp = cw2 + (size_t)wt * 16384 + c;
  float a0 = 0, a1 = 0, a2 = 0, a3 = 0, p0 = 0, p1 = 0, p2 = 0, p3 = 0;
  for (int i = 0; i < 128; ++i) {
    float v1 = f1[i], v4 = f4[i];
    float4 cv = *(const float4*)(cwp + (size_t)i * 128);
    a0 += v1 * cv.x; a1 += v1 * cv.y; a2 += v1 * cv.z; a3 += v1 * cv.w;
    p0 += v4 * cv.x; p1 += v4 * cv.y; p2 += v4 * cv.z; p3 += v4 * cv.w;
  }
  *(float4*)(&P_lds[o_l][c]) = make_float4(p0, p1, p2, p3);
  __syncthreads();
  const float* g = gkT + w * 16384 + c;
  for (int j = 0; j < 128; ++j) {
    float pv = P_lds[o_l][j];
    float4 g4 = *(const float4*)(g + (size_t)j * 128);
    a0 += pv * g4.x; a1 += pv * g4.y; a2 += pv * g4.z; a3 += pv * g4.w;
  }
  *(float4*)(M + (size_t)wt * 16384 + o * 128 + c) = make_float4(a0, a1, a2, a3);
}

// K5: Keff_bf16[b][t][o][c] = sum_w ww[b,w]*M[w][t][o][c] + fsum[o]*gk_b[c]
__global__ void k5_keff(const float* __restrict__ M, const float* __restrict__ ww,
                        const float* __restrict__ fsum, const float* __restrict__ gk_b,
                        u16* __restrict__ keff) {
  int gid = blockIdx.x * 256 + threadIdx.x;   // 0..294911
  int b = gid / 36864;
  int rem = gid % 36864;                      // t*4096 + o*32 + cq
  int o = (rem % 4096) / 32;
  int c = (rem % 32) * 4;
  float w0 = ww[b * 4 + 0], w1 = ww[b * 4 + 1], w2 = ww[b * 4 + 2], w3 = ww[b * 4 + 3];
  int mi = rem * 4;                           // == t*16384 + o*128 + c
  float4 m0 = *(const float4*)(M + 0 * 147456 + mi);
  float4 m1 = *(const float4*)(M + 1 * 147456 + mi);
  float4 m2 = *(const float4*)(M + 2 * 147456 + mi);
  float4 m3 = *(const float4*)(M + 3 * 147456 + mi);
  float fs = fsum[o];
  float4 gb = *(const float4*)(gk_b + c);
  float r0 = w0 * m0.x + w1 * m1.x + w2 * m2.x + w3 * m3.x + fs * gb.x;
  float r1 = w0 * m0.y + w1 * m1.y + w2 * m2.y + w3 * m3.y + fs * gb.y;
  float r2 = w0 * m0.z + w1 * m1.z + w2 * m2.z + w3 * m3.z + fs * gb.z;
  float r3 = w0 * m0.w + w1 * m1.w + w2 * m2.w + w3 * m3.w + fs * gb.w;
  u16x4 st = { f2bf(r0), f2bf(r1), f2bf(r2), f2bf(r3) };
  *(u16x4*)(keff + (size_t)b * 147456 + mi) = st;
}

// K6: per-batch 3x3 C->C conv as 9 accumulated bf16 MFMA GEMMs.
// Block = (b, half-row): out tile 64 px x 128 o; grid 2048 = 2x residency -> sliding
// row window per XCD (~2.2MB, fits 4MB L2). 4 waves in 2x2 (32m x 64n each).
// XOR-swizzled single 32KB LDS weight buffer; nontemporal out stores keep L2 clean.
__global__ __launch_bounds__(256, 4) void k6_conv(
    const u16* __restrict__ xpad, const u16* __restrict__ keff,
    const float* __restrict__ fusion_b, float* __restrict__ out) {
  __shared__ __align__(16) u16 wlds[128 * 128];
  const int tid = threadIdx.x;
  const int blk = blockIdx.x;
  const int b = blk & 7;            // XCD affinity: batch <-> XCD
  const int ph = blk >> 3;          // 0..255 ascending -> sliding row window
  const int p = ph >> 1;
  const int m0 = (ph & 1) * 64;
  const int wid = tid >> 6;
  const int lane = tid & 63;
  const int wm = (wid & 1) * 32;
  const int wn = (wid >> 1) * 64;
  const int quad = lane >> 4;
  const int l16 = lane & 15;

  f32x4 acc[2][4];
  #pragma unroll
  for (int i = 0; i < 2; ++i)
    #pragma unroll
    for (int j = 0; j < 4; ++j)
      acc[i][j] = (f32x4){0.f, 0.f, 0.f, 0.f};

  const u16* kb = keff + (size_t)b * 147456;
  bf16x8 streg[8];

  auto stage_load = [&](int tap) {
    const u16* src = kb + tap * 16384;
    #pragma unroll
    for (int it = 0; it < 8; ++it)
      streg[it] = *(const bf16x8*)(src + (it * 256 + tid) * 8);
  };
  // XOR swizzle: element row n (o-channel), col-octet cb -> offset n*128 + ((cb^(n&15))*8)
  auto stage_write = [&]() {
    #pragma unroll
    for (int it = 0; it < 8; ++it) {
      int e = it * 256 + tid;
      int n = e >> 4, cb = e & 15;
      *(bf16x8*)(&wlds[(n << 7) + ((cb ^ (n & 15)) << 3)]) = streg[it];
    }
  };

  stage_load(0);
  stage_write();
  __syncthreads();

  const size_t xrow = 130 * 128;
  const u16* xb = xpad + (size_t)b * 130 * xrow;

  for (int tap = 0; tap < 9; ++tap) {
    if (tap < 8) stage_load(tap + 1);           // global->reg, overlaps MFMA below
    const int dh = tap / 3 - 1;
    const int dw = tap % 3 - 1;
    const u16* arow = xb + (size_t)(p + 1 + dh) * xrow + (size_t)(1 + dw) * 128
                      + (size_t)m0 * 128;
    #pragma unroll
    for (int kc = 0; kc < 4; ++kc) {
      const int c0 = kc * 32 + quad * 8;
      const int cb = kc * 4 + quad;             // col-octet index
      bf16x8 a[2], bb[4];
      #pragma unroll
      for (int i = 0; i < 2; ++i)
        a[i] = *(const bf16x8*)(arow + (size_t)(wm + i * 16 + l16) * 128 + c0);
      #pragma unroll
      for (int j = 0; j < 4; ++j) {
        int n = wn + j * 16 + l16;              // n&15 == l16
        bb[j] = *(const bf16x8*)(&wlds[(n << 7) + ((cb ^ l16) << 3)]);
      }
      #pragma unroll
      for (int i = 0; i < 2; ++i)
        #pragma unroll
        for (int j = 0; j < 4; ++j)
          acc[i][j] = __builtin_amdgcn_mfma_f32_16x16x32_bf16(a[i], bb[j], acc[i][j], 0, 0, 0);
    }
    __syncthreads();                            // all waves done reading wlds
    if (tap < 8) {
      stage_write();
      __syncthreads();                          // writes visible to all waves
    }
  }

  float fb[4];
  #pragma unroll
  for (int j = 0; j < 4; ++j) fb[j] = fusion_b[wn + j * 16 + l16];
  float* outb = out + ((size_t)b * 16384 + (size_t)p * 128) * 128;
  #pragma unroll
  for (int i = 0; i < 2; ++i)
    #pragma unroll
    for (int r = 0; r < 4; ++r) {
      const int m = m0 + wm + i * 16 + quad * 4 + r;
      #pragma unroll
      for (int j = 0; j < 4; ++j)
        __builtin_nontemporal_store(acc[i][j][r] + fb[j],
                                    &outb[(size_t)m * 128 + (wn + j * 16 + l16)]);
    }
}

extern "C" void kernel_launch(void* const* d_in, const int* in_sizes, int n_in,
                              void* d_out, int out_size, void* d_ws, size_t ws_size,
                              hipStream_t stream) {
  const float* x        = (const float*)d_in[0];
  const float* conv1_w  = (const float*)d_in[1];
  const float* dc_w     = (const float*)d_in[2];
  const float* dc_b     = (const float*)d_in[3];
  const float* l1_w     = (const float*)d_in[4];
  const float* l1_b     = (const float*)d_in[5];
  const float* l2_w     = (const float*)d_in[6];
  const float* l2_b     = (const float*)d_in[7];
  const float* gk_w     = (const float*)d_in[8];
  const float* gk_b     = (const float*)d_in[9];
  const float* fusion_w = (const float*)d_in[10];
  const float* fusion_b = (const float*)d_in[11];
  float* out = (float*)d_out;
  char* ws = (char*)d_ws;

  float* agg  = (float*)(ws + OFF_AGG);
  float* ww   = (float*)(ws + OFF_WW);
  float* R2   = (float*)(ws + OFF_R);
  float* fsum = (float*)(ws + OFF_FSUM);
  float* gkT  = (float*)(ws + OFF_GKT);
  float* M    = (float*)(ws + OFF_M);
  float* cw2  = (float*)(ws + OFF_KEFF);   // cw2 (prep) and keff share the slot:
  u16* keff   = (u16*)(ws + OFF_KEFF);     // cw2 is dead before k5 writes keff
  u16* xpad   = (u16*)(ws + OFF_XPAD);

  hipMemsetAsync(agg, 0, 81920, stream);
  k1_pad_agg<<<dim3(130, 8), 512, 0, stream>>>(x, xpad, agg);
  kCW<<<2304, 256, 0, stream>>>(conv1_w, cw2);
  k_small<<<293, 256, 0, stream>>>(dc_w, cw2, gk_w, fusion_w, R2, gkT, fsum);
  k2_ww<<<8, 256, 0, stream>>>(x, agg, R2, dc_b, l1_w, l1_b, l2_w, l2_b, ww);
  k34_M<<<576, 256, 0, stream>>>(fusion_w, cw2, gkT, M);
  k5_keff<<<1152, 256, 0, stream>>>(M, ww, fsum, gk_b, keff);
  k6_conv<<<2048, 256, 0, stream>>>(xpad, keff, fusion_b, out);
}